// Round 5
// baseline (754.139 us; speedup 1.0000x reference)
//
#include <hip/hip_runtime.h>
#include <hip/hip_bf16.h>
#include <hip/hip_fp16.h>
#include <math.h>

// ---------------------------------------------------------------------------
// 2-layer GAT on MI355X (gfx950).
// L1: in=128, H=8, C=32 (concat->256) +bias1, ELU.  L2: in=256, H=1, C=64 +bias2.
// R5: back to R3's line-count-optimal aggregation (full-row H4 gathers,
// 8-deep batching); heavy fusion to cut dispatches 16->11 and kill redundant
// passes: att coefficients fused into GEMM epilogue (in-wave shuffle reduce,
// no atomics), xs1+denominator fused into scatter, xs2 accumulates denom2.
// Aggregation kernels are single-pass (denominators preaccumulated).
// ---------------------------------------------------------------------------

#define LEAKY(e) ((e) > 0.f ? (e) : 0.2f * (e))

struct __align__(8) H4 { __half2 a, b; };  // 4 halves

// ------- tiled GEMM + fused attention coefficients -------------------------
// C[n,NTOT] = A[n,K] @ B[K,NTOT], fp16 flat out, 128x64 tile / 256 thr.
// Epilogue: per-row dot with att_src/att_dst reduced across the lanes that
// hold the row's channels (NTOT=256: 8 lanes = one 32-ch head; NTOT=64: 16
// lanes = the whole row). Exactly one thread stores each (row,head) -> no
// atomics, no pre-zero.
template <int K, int NTOT>
__global__ __launch_bounds__(256) void gemm_att_kernel(
    const float* __restrict__ A, const float* __restrict__ B,
    __half* __restrict__ Ch, const float* __restrict__ att_src,
    const float* __restrict__ att_dst, float* __restrict__ a_src,
    float* __restrict__ a_dst, int n) {
  const int KC = 64;
  __shared__ float As[KC][132];
  __shared__ float Bs[KC][68];
  int t = threadIdx.x;
  int tx = t & 15, ty = t >> 4;
  int m0 = blockIdx.x * 128;
  int c0 = blockIdx.y * 64;
  float acc[8][4] = {};
  for (int kc = 0; kc < K; kc += KC) {
#pragma unroll
    for (int rep = 0; rep < 8; rep++) {
      int lin = rep * 256 + t;
      int r = lin & 127;
      int k4 = (lin >> 7) * 4;
      int gr = m0 + r;
      float4 v = (gr < n) ? *(const float4*)(A + (size_t)gr * K + kc + k4)
                          : make_float4(0.f, 0.f, 0.f, 0.f);
      As[k4 + 0][r] = v.x;
      As[k4 + 1][r] = v.y;
      As[k4 + 2][r] = v.z;
      As[k4 + 3][r] = v.w;
    }
#pragma unroll
    for (int rep = 0; rep < 4; rep++) {
      int lin = rep * 256 + t;
      int r = lin >> 4;
      int c4 = (lin & 15) * 4;
      *(float4*)&Bs[r][c4] = *(const float4*)(B + (size_t)(kc + r) * NTOT + c0 + c4);
    }
    __syncthreads();
#pragma unroll 4
    for (int k = 0; k < KC; k++) {
      float4 a0 = *(const float4*)&As[k][ty * 8];
      float4 a1 = *(const float4*)&As[k][ty * 8 + 4];
      float4 b4 = *(const float4*)&Bs[k][tx * 4];
      float av[8] = {a0.x, a0.y, a0.z, a0.w, a1.x, a1.y, a1.z, a1.w};
      float bv[4] = {b4.x, b4.y, b4.z, b4.w};
#pragma unroll
      for (int i = 0; i < 8; i++)
#pragma unroll
        for (int j = 0; j < 4; j++) acc[i][j] = fmaf(av[i], bv[j], acc[i][j]);
    }
    __syncthreads();
  }
  int c = c0 + tx * 4;  // global output channel (4-aligned)
  float4 avs = *(const float4*)(att_src + c);
  float4 avd = *(const float4*)(att_dst + c);
#pragma unroll
  for (int i = 0; i < 8; i++) {
    int gr = m0 + ty * 8 + i;
    // fp16 store
    if (gr < n) {
      H4 hv;
      hv.a = __floats2half2_rn(acc[i][0], acc[i][1]);
      hv.b = __floats2half2_rn(acc[i][2], acc[i][3]);
      *(H4*)(Ch + (size_t)gr * NTOT + c) = hv;
    }
    // attention partials for this row
    float ps = acc[i][0] * avs.x + acc[i][1] * avs.y + acc[i][2] * avs.z +
               acc[i][3] * avs.w;
    float pd = acc[i][0] * avd.x + acc[i][1] * avd.y + acc[i][2] * avd.z +
               acc[i][3] * avd.w;
    if (NTOT == 256) {
      // 8 lanes (tx&8 group) hold one head's 32 channels
      ps += __shfl_xor(ps, 1, 64);
      ps += __shfl_xor(ps, 2, 64);
      ps += __shfl_xor(ps, 4, 64);
      pd += __shfl_xor(pd, 1, 64);
      pd += __shfl_xor(pd, 2, 64);
      pd += __shfl_xor(pd, 4, 64);
      if ((tx & 7) == 0 && gr < n) {
        int head = c >> 5;
        a_src[(size_t)gr * 8 + head] = ps;
        a_dst[(size_t)gr * 8 + head] = pd;
      }
    } else {
      // 16 lanes hold the whole 64-ch row
      ps += __shfl_xor(ps, 1, 64);
      ps += __shfl_xor(ps, 2, 64);
      ps += __shfl_xor(ps, 4, 64);
      ps += __shfl_xor(ps, 8, 64);
      pd += __shfl_xor(pd, 1, 64);
      pd += __shfl_xor(pd, 2, 64);
      pd += __shfl_xor(pd, 4, 64);
      pd += __shfl_xor(pd, 8, 64);
      if (tx == 0 && gr < n) {
        a_src[gr] = ps;
        a_dst[gr] = pd;
      }
    }
  }
}

// ------------------------- CSR construction --------------------------------
__global__ __launch_bounds__(256) void hist_kernel(
    const int* __restrict__ ei, int E, int n, int* __restrict__ deg) {
  int idx = blockIdx.x * 256 + threadIdx.x;
  if (idx >= E + n) return;
  int d = (idx < E) ? ei[E + idx] : (idx - E);
  atomicAdd(&deg[d], 1);
}

__global__ __launch_bounds__(256) void scan1_kernel(
    const int* __restrict__ deg, int* __restrict__ bsum, int n) {
  __shared__ int ws[4];
  int t = threadIdx.x;
  int i = blockIdx.x * 256 + t;
  int v = (i < n) ? deg[i] : 0;
  int wv = v;
#pragma unroll
  for (int o = 32; o; o >>= 1) wv += __shfl_xor(wv, o, 64);
  if ((t & 63) == 0) ws[t >> 6] = wv;
  __syncthreads();
  if (t == 0) bsum[blockIdx.x] = ws[0] + ws[1] + ws[2] + ws[3];
}

__global__ __launch_bounds__(1024) void scan2_kernel(int* __restrict__ bsum,
                                                     int nb) {
  __shared__ int sb[1024];
  int t = threadIdx.x;
  int v = (t < nb) ? bsum[t] : 0;
  sb[t] = v;
  __syncthreads();
  int x = v;
  for (int off = 1; off < 1024; off <<= 1) {
    int y = (t >= off) ? sb[t - off] : 0;
    __syncthreads();
    x += y;
    sb[t] = x;
    __syncthreads();
  }
  if (t < nb) bsum[t] = x - v;  // exclusive
}

__global__ __launch_bounds__(256) void scan3_kernel(
    const int* __restrict__ deg, const int* __restrict__ bsum,
    int* __restrict__ rowptr, int* __restrict__ cursor, int n) {
  __shared__ int sb[256];
  int t = threadIdx.x;
  int i = blockIdx.x * 256 + t;
  int v = (i < n) ? deg[i] : 0;
  sb[t] = v;
  __syncthreads();
  int x = v;
  for (int off = 1; off < 256; off <<= 1) {
    int y = (t >= off) ? sb[t - off] : 0;
    __syncthreads();
    x += y;
    sb[t] = x;
    __syncthreads();
  }
  int excl = x - v + bsum[blockIdx.x];
  if (i < n) {
    rowptr[i] = excl;
    cursor[i] = excl;
  }
  if (i == n - 1) rowptr[n] = excl + v;
}

// ------- scatter + fused layer-1 numerators + denominator atomics ----------
__global__ __launch_bounds__(256) void scatter_kernel(
    const int* __restrict__ ei, int E, int n, int* __restrict__ cursor,
    int* __restrict__ csr_src, int* __restrict__ csr_dst,
    const float* __restrict__ a_src1, const float* __restrict__ a_dst1,
    float* __restrict__ xs1, float* __restrict__ denom1) {
  int idx = blockIdx.x * 256 + threadIdx.x;
  if (idx >= E + n) return;
  int s, d;
  if (idx < E) {
    s = ei[idx];
    d = ei[E + idx];
  } else {
    s = d = idx - E;
  }
  int pos = atomicAdd(&cursor[d], 1);
  csr_src[pos] = s;
  csr_dst[pos] = d;
  float4 s0 = *(const float4*)(a_src1 + (size_t)s * 8);
  float4 s1 = *(const float4*)(a_src1 + (size_t)s * 8 + 4);
  float4 d0 = *(const float4*)(a_dst1 + (size_t)d * 8);
  float4 d1 = *(const float4*)(a_dst1 + (size_t)d * 8 + 4);
  float w[8];
  float es[8] = {s0.x + d0.x, s0.y + d0.y, s0.z + d0.z, s0.w + d0.w,
                 s1.x + d1.x, s1.y + d1.y, s1.z + d1.z, s1.w + d1.w};
#pragma unroll
  for (int h = 0; h < 8; h++) {
    float e = LEAKY(es[h]);
    w[h] = __expf(e);
  }
  *(float4*)(xs1 + (size_t)pos * 8) = make_float4(w[0], w[1], w[2], w[3]);
  *(float4*)(xs1 + (size_t)pos * 8 + 4) = make_float4(w[4], w[5], w[6], w[7]);
#pragma unroll
  for (int h = 0; h < 8; h++) atomicAdd(&denom1[(size_t)d * 8 + h], w[h]);
}

// ----- per-edge exp(leaky(e)) layer 2 + denominator atomics ---------------
__global__ __launch_bounds__(256) void xs2_kernel(
    const int* __restrict__ csr_src, const int* __restrict__ csr_dst,
    const float* __restrict__ a_src, const float* __restrict__ a_dst,
    float* __restrict__ xs2, float* __restrict__ denom2, int Etot) {
  int i = blockIdx.x * 256 + threadIdx.x;
  if (i >= Etot) return;
  int d = csr_dst[i];
  float e = a_src[csr_src[i]] + a_dst[d];
  e = LEAKY(e);
  float w = __expf(e);
  xs2[i] = w;
  atomicAdd(&denom2[d], w);
}

// ------- layer-1 aggregation: one wave per dst; lane owns 4 channels -------
// single pass: denominator preaccumulated in denom1.
__global__ __launch_bounds__(256) void agg1_kernel(
    const int* __restrict__ rowptr, const int* __restrict__ csr_src,
    const float* __restrict__ xs1, const float* __restrict__ denom1,
    const __half* __restrict__ h1h, const float* __restrict__ bias,
    float* __restrict__ h_act, int n) {
  int w = threadIdx.x >> 6, l = threadIdx.x & 63;
  int d = blockIdx.x * 4 + w;
  if (d >= n) return;
  int base = rowptr[d], cnt = rowptr[d + 1] - base;
  const float* xp = xs1 + (size_t)base * 8;
  int hh = l >> 3;  // head of owned channels 4l..4l+3
  float rh = 1.f / (denom1[(size_t)d * 8 + hh] + 1e-16f);
  float4 acc = make_float4(0.f, 0.f, 0.f, 0.f);
  int i = 0;
  for (; i + 8 <= cnt; i += 8) {
    int s[8];
    float xv[8];
    H4 v[8];
#pragma unroll
    for (int j = 0; j < 8; j++) s[j] = csr_src[base + i + j];
#pragma unroll
    for (int j = 0; j < 8; j++) xv[j] = xp[(i + j) * 8 + hh];
#pragma unroll
    for (int j = 0; j < 8; j++)
      v[j] = *(const H4*)(h1h + (size_t)s[j] * 256 + 4 * l);
#pragma unroll
    for (int j = 0; j < 8; j++) {
      float a = xv[j] * rh;
      float2 p0 = __half22float2(v[j].a), p1 = __half22float2(v[j].b);
      acc.x = fmaf(p0.x, a, acc.x);
      acc.y = fmaf(p0.y, a, acc.y);
      acc.z = fmaf(p1.x, a, acc.z);
      acc.w = fmaf(p1.y, a, acc.w);
    }
  }
  for (; i < cnt; i++) {
    int s = csr_src[base + i];
    float a = xp[i * 8 + hh] * rh;
    H4 v = *(const H4*)(h1h + (size_t)s * 256 + 4 * l);
    float2 p0 = __half22float2(v.a), p1 = __half22float2(v.b);
    acc.x = fmaf(p0.x, a, acc.x);
    acc.y = fmaf(p0.y, a, acc.y);
    acc.z = fmaf(p1.x, a, acc.z);
    acc.w = fmaf(p1.y, a, acc.w);
  }
  float4 b = *(const float4*)(bias + 4 * l);
  float4 o;
  o.x = acc.x + b.x;
  o.y = acc.y + b.y;
  o.z = acc.z + b.z;
  o.w = acc.w + b.w;
  o.x = o.x > 0.f ? o.x : expm1f(o.x);
  o.y = o.y > 0.f ? o.y : expm1f(o.y);
  o.z = o.z > 0.f ? o.z : expm1f(o.z);
  o.w = o.w > 0.f ? o.w : expm1f(o.w);
  *(float4*)(h_act + (size_t)d * 256 + 4 * l) = o;
}

// ------- layer-2 aggregation: wave per dst, 2 edge-slots x 32 ch-pairs -----
__global__ __launch_bounds__(256) void agg2_kernel(
    const int* __restrict__ rowptr, const int* __restrict__ csr_src,
    const float* __restrict__ xs2, const float* __restrict__ denom2,
    const __half* __restrict__ h2h, const float* __restrict__ bias,
    float* __restrict__ out, int n) {
  int w = threadIdx.x >> 6, l = threadIdx.x & 63;
  int d = blockIdx.x * 4 + w;
  if (d >= n) return;
  int base = rowptr[d], cnt = rowptr[d + 1] - base;
  float rinv = 1.f / (denom2[d] + 1e-16f);
  int e = l >> 5;
  int c2 = (l & 31) * 2;
  float2 acc = make_float2(0.f, 0.f);
  int i = 0;
  for (; i + 16 <= cnt; i += 16) {
    int s[8];
    float xv[8];
    __half2 v[8];
#pragma unroll
    for (int j = 0; j < 8; j++) {
      int idx = base + i + j * 2 + e;
      s[j] = csr_src[idx];
      xv[j] = xs2[idx];
    }
#pragma unroll
    for (int j = 0; j < 8; j++)
      v[j] = *(const __half2*)(h2h + (size_t)s[j] * 64 + c2);
#pragma unroll
    for (int j = 0; j < 8; j++) {
      float a = xv[j] * rinv;
      float2 f = __half22float2(v[j]);
      acc.x = fmaf(f.x, a, acc.x);
      acc.y = fmaf(f.y, a, acc.y);
    }
  }
  for (; i + e < cnt; i += 2) {
    int idx = base + i + e;
    int s = csr_src[idx];
    float a = xs2[idx] * rinv;
    float2 f = __half22float2(*(const __half2*)(h2h + (size_t)s * 64 + c2));
    acc.x = fmaf(f.x, a, acc.x);
    acc.y = fmaf(f.y, a, acc.y);
  }
  acc.x += __shfl_xor(acc.x, 32, 64);
  acc.y += __shfl_xor(acc.y, 32, 64);
  if (l < 32) {
    float2 b = *(const float2*)(bias + c2);
    *(float2*)(out + (size_t)d * 64 + c2) = make_float2(acc.x + b.x, acc.y + b.y);
  }
}

// ---------------------------------------------------------------------------
extern "C" void kernel_launch(void* const* d_in, const int* in_sizes, int n_in,
                              void* d_out, int out_size, void* d_ws, size_t ws_size,
                              hipStream_t stream) {
  const float* x        = (const float*)d_in[0];
  const int*   ei       = (const int*)d_in[1];
  const float* W1       = (const float*)d_in[3];
  const float* att_src1 = (const float*)d_in[4];
  const float* att_dst1 = (const float*)d_in[5];
  const float* bias1    = (const float*)d_in[6];
  const float* W2       = (const float*)d_in[7];
  const float* att_src2 = (const float*)d_in[8];
  const float* att_dst2 = (const float*)d_in[9];
  const float* bias2    = (const float*)d_in[10];
  float* out = (float*)d_out;

  int N = in_sizes[0] / 128;
  int E = in_sizes[1] / 2;
  int Etot = E + N;
  int nb = (N + 255) / 256;

  char* ws = (char*)d_ws;
  size_t off = 0;
  auto carve = [&](size_t bytes) -> void* {
    void* p = ws + off;
    off += (bytes + 255) & ~(size_t)255;
    return p;
  };
  __half* h1h   = (__half*)carve((size_t)N * 256 * 2);  // [N][256]
  __half* h2h   = (__half*)carve((size_t)N * 64 * 2);   // [N][64]
  float* h_act  = (float*)carve((size_t)N * 256 * 4);
  float* a_src1 = (float*)carve((size_t)N * 8 * 4);     // [N][8]
  float* a_dst1 = (float*)carve((size_t)N * 8 * 4);
  float* a_src2 = (float*)carve((size_t)N * 4);
  float* a_dst2 = (float*)carve((size_t)N * 4);
  int* rowptr   = (int*)carve((size_t)(N + 1) * 4);
  int* cursor   = (int*)carve((size_t)N * 4);
  int* bsum     = (int*)carve((size_t)nb * 4);
  // contiguous zero region: deg + denom1 + denom2
  char* zero0   = ws + off;
  int* deg      = (int*)carve((size_t)N * 4);
  float* denom1 = (float*)carve((size_t)N * 8 * 4);
  float* denom2 = (float*)carve((size_t)N * 4);
  size_t zbytes = (ws + off) - zero0;
  int* csr_src  = (int*)carve((size_t)Etot * 4);
  int* csr_dst  = (int*)carve((size_t)Etot * 4);
  float* xs1    = (float*)carve((size_t)Etot * 8 * 4);
  float* xs2    = (float*)carve((size_t)Etot * 4);
  (void)ws_size; (void)n_in; (void)out_size;

  // zero: deg + denominators
  hipMemsetAsync(zero0, 0, zbytes, stream);
  // layer-1 projection + fused attention coefficients
  {
    dim3 g((N + 127) / 128, 4);
    gemm_att_kernel<128, 256><<<g, 256, 0, stream>>>(
        x, W1, h1h, att_src1, att_dst1, a_src1, a_dst1, N);
  }
  // CSR build
  hist_kernel<<<(Etot + 255) / 256, 256, 0, stream>>>(ei, E, N, deg);
  scan1_kernel<<<nb, 256, 0, stream>>>(deg, bsum, N);
  scan2_kernel<<<1, 1024, 0, stream>>>(bsum, nb);
  scan3_kernel<<<nb, 256, 0, stream>>>(deg, bsum, rowptr, cursor, N);
  // scatter + layer-1 numerators + denominators
  scatter_kernel<<<(Etot + 255) / 256, 256, 0, stream>>>(
      ei, E, N, cursor, csr_src, csr_dst, a_src1, a_dst1, xs1, denom1);
  // layer-1 aggregation (+bias+ELU)
  agg1_kernel<<<(N + 3) / 4, 256, 0, stream>>>(rowptr, csr_src, xs1, denom1,
                                               h1h, bias1, h_act, N);
  // layer-2 projection + fused attention coefficients
  {
    dim3 g((N + 127) / 128, 1);
    gemm_att_kernel<256, 64><<<g, 256, 0, stream>>>(
        h_act, W2, h2h, att_src2, att_dst2, a_src2, a_dst2, N);
  }
  // layer-2 numerators + denominators, then aggregation
  xs2_kernel<<<(Etot + 255) / 256, 256, 0, stream>>>(csr_src, csr_dst, a_src2,
                                                     a_dst2, xs2, denom2, Etot);
  agg2_kernel<<<(N + 3) / 4, 256, 0, stream>>>(rowptr, csr_src, xs2, denom2,
                                               h2h, bias2, out, N);
}

// Round 6
// 397.739 us; speedup vs baseline: 1.8961x; 1.8961x over previous
//
#include <hip/hip_runtime.h>
#include <hip/hip_bf16.h>
#include <hip/hip_fp16.h>
#include <math.h>

// ---------------------------------------------------------------------------
// 2-layer GAT on MI355X (gfx950).
// L1: in=128, H=8, C=32 (concat->256) +bias1, ELU.  L2: in=256, H=1, C=64 +bias2.
// R6: attention logits recomputed in-kernel (a_src tables are L2-resident:
// 1.6MB / 200KB) -> xs1/xs2/denom arrays and their kernels deleted; scatter
// writes only csr_src (4B/edge; R5's fused 32B scattered writes were a 380us
// write-allocate disaster). GEMM+att-coefficient fusion kept (register-
// resident epilogue). 10 dispatches.
// ---------------------------------------------------------------------------

#define LEAKY(e) ((e) > 0.f ? (e) : 0.2f * (e))

struct __align__(8) H4 { __half2 a, b; };  // 4 halves

// ------- tiled GEMM + fused attention coefficients -------------------------
// C[n,NTOT] = A[n,K] @ B[K,NTOT], fp16 flat out, 128x64 tile / 256 thr.
template <int K, int NTOT>
__global__ __launch_bounds__(256) void gemm_att_kernel(
    const float* __restrict__ A, const float* __restrict__ B,
    __half* __restrict__ Ch, const float* __restrict__ att_src,
    const float* __restrict__ att_dst, float* __restrict__ a_src,
    float* __restrict__ a_dst, int n) {
  const int KC = 64;
  __shared__ float As[KC][132];
  __shared__ float Bs[KC][68];
  int t = threadIdx.x;
  int tx = t & 15, ty = t >> 4;
  int m0 = blockIdx.x * 128;
  int c0 = blockIdx.y * 64;
  float acc[8][4] = {};
  for (int kc = 0; kc < K; kc += KC) {
#pragma unroll
    for (int rep = 0; rep < 8; rep++) {
      int lin = rep * 256 + t;
      int r = lin & 127;
      int k4 = (lin >> 7) * 4;
      int gr = m0 + r;
      float4 v = (gr < n) ? *(const float4*)(A + (size_t)gr * K + kc + k4)
                          : make_float4(0.f, 0.f, 0.f, 0.f);
      As[k4 + 0][r] = v.x;
      As[k4 + 1][r] = v.y;
      As[k4 + 2][r] = v.z;
      As[k4 + 3][r] = v.w;
    }
#pragma unroll
    for (int rep = 0; rep < 4; rep++) {
      int lin = rep * 256 + t;
      int r = lin >> 4;
      int c4 = (lin & 15) * 4;
      *(float4*)&Bs[r][c4] = *(const float4*)(B + (size_t)(kc + r) * NTOT + c0 + c4);
    }
    __syncthreads();
#pragma unroll 4
    for (int k = 0; k < KC; k++) {
      float4 a0 = *(const float4*)&As[k][ty * 8];
      float4 a1 = *(const float4*)&As[k][ty * 8 + 4];
      float4 b4 = *(const float4*)&Bs[k][tx * 4];
      float av[8] = {a0.x, a0.y, a0.z, a0.w, a1.x, a1.y, a1.z, a1.w};
      float bv[4] = {b4.x, b4.y, b4.z, b4.w};
#pragma unroll
      for (int i = 0; i < 8; i++)
#pragma unroll
        for (int j = 0; j < 4; j++) acc[i][j] = fmaf(av[i], bv[j], acc[i][j]);
    }
    __syncthreads();
  }
  int c = c0 + tx * 4;  // global output channel (4-aligned)
  float4 avs = *(const float4*)(att_src + c);
  float4 avd = *(const float4*)(att_dst + c);
#pragma unroll
  for (int i = 0; i < 8; i++) {
    int gr = m0 + ty * 8 + i;
    if (gr < n) {
      H4 hv;
      hv.a = __floats2half2_rn(acc[i][0], acc[i][1]);
      hv.b = __floats2half2_rn(acc[i][2], acc[i][3]);
      *(H4*)(Ch + (size_t)gr * NTOT + c) = hv;
    }
    float ps = acc[i][0] * avs.x + acc[i][1] * avs.y + acc[i][2] * avs.z +
               acc[i][3] * avs.w;
    float pd = acc[i][0] * avd.x + acc[i][1] * avd.y + acc[i][2] * avd.z +
               acc[i][3] * avd.w;
    if (NTOT == 256) {
      ps += __shfl_xor(ps, 1, 64);
      ps += __shfl_xor(ps, 2, 64);
      ps += __shfl_xor(ps, 4, 64);
      pd += __shfl_xor(pd, 1, 64);
      pd += __shfl_xor(pd, 2, 64);
      pd += __shfl_xor(pd, 4, 64);
      if ((tx & 7) == 0 && gr < n) {
        int head = c >> 5;
        a_src[(size_t)gr * 8 + head] = ps;
        a_dst[(size_t)gr * 8 + head] = pd;
      }
    } else {
      ps += __shfl_xor(ps, 1, 64);
      ps += __shfl_xor(ps, 2, 64);
      ps += __shfl_xor(ps, 4, 64);
      ps += __shfl_xor(ps, 8, 64);
      pd += __shfl_xor(pd, 1, 64);
      pd += __shfl_xor(pd, 2, 64);
      pd += __shfl_xor(pd, 4, 64);
      pd += __shfl_xor(pd, 8, 64);
      if (tx == 0 && gr < n) {
        a_src[gr] = ps;
        a_dst[gr] = pd;
      }
    }
  }
}

// ------------------------- CSR construction --------------------------------
__global__ __launch_bounds__(256) void hist_kernel(
    const int* __restrict__ ei, int E, int n, int* __restrict__ deg) {
  int idx = blockIdx.x * 256 + threadIdx.x;
  if (idx >= E + n) return;
  int d = (idx < E) ? ei[E + idx] : (idx - E);
  atomicAdd(&deg[d], 1);
}

__global__ __launch_bounds__(256) void scan1_kernel(
    const int* __restrict__ deg, int* __restrict__ bsum, int n) {
  __shared__ int ws[4];
  int t = threadIdx.x;
  int i = blockIdx.x * 256 + t;
  int v = (i < n) ? deg[i] : 0;
  int wv = v;
#pragma unroll
  for (int o = 32; o; o >>= 1) wv += __shfl_xor(wv, o, 64);
  if ((t & 63) == 0) ws[t >> 6] = wv;
  __syncthreads();
  if (t == 0) bsum[blockIdx.x] = ws[0] + ws[1] + ws[2] + ws[3];
}

__global__ __launch_bounds__(1024) void scan2_kernel(int* __restrict__ bsum,
                                                     int nb) {
  __shared__ int sb[1024];
  int t = threadIdx.x;
  int v = (t < nb) ? bsum[t] : 0;
  sb[t] = v;
  __syncthreads();
  int x = v;
  for (int off = 1; off < 1024; off <<= 1) {
    int y = (t >= off) ? sb[t - off] : 0;
    __syncthreads();
    x += y;
    sb[t] = x;
    __syncthreads();
  }
  if (t < nb) bsum[t] = x - v;  // exclusive
}

__global__ __launch_bounds__(256) void scan3_kernel(
    const int* __restrict__ deg, const int* __restrict__ bsum,
    int* __restrict__ rowptr, int* __restrict__ cursor, int n) {
  __shared__ int sb[256];
  int t = threadIdx.x;
  int i = blockIdx.x * 256 + t;
  int v = (i < n) ? deg[i] : 0;
  sb[t] = v;
  __syncthreads();
  int x = v;
  for (int off = 1; off < 256; off <<= 1) {
    int y = (t >= off) ? sb[t - off] : 0;
    __syncthreads();
    x += y;
    sb[t] = x;
    __syncthreads();
  }
  int excl = x - v + bsum[blockIdx.x];
  if (i < n) {
    rowptr[i] = excl;
    cursor[i] = excl;
  }
  if (i == n - 1) rowptr[n] = excl + v;
}

__global__ __launch_bounds__(256) void scatter_kernel(
    const int* __restrict__ ei, int E, int n, int* __restrict__ cursor,
    int* __restrict__ csr_src) {
  int idx = blockIdx.x * 256 + threadIdx.x;
  if (idx >= E + n) return;
  int s, d;
  if (idx < E) {
    s = ei[idx];
    d = ei[E + idx];
  } else {
    s = d = idx - E;
  }
  int pos = atomicAdd(&cursor[d], 1);
  csr_src[pos] = s;
}

// ------- layer-1 aggregation: one wave per dst; logits recomputed ----------
// pass 1 (denominator): lane l -> edge-slot l>>3, head l&7.
// pass 2 (accumulate): lane l -> channels 4l..4l+3, head l>>3.
__global__ __launch_bounds__(256) void agg1_kernel(
    const int* __restrict__ rowptr, const int* __restrict__ csr_src,
    const float* __restrict__ a_src1, const float* __restrict__ a_dst1,
    const __half* __restrict__ h1h, const float* __restrict__ bias,
    float* __restrict__ h_act, int n) {
  int w = threadIdx.x >> 6, l = threadIdx.x & 63;
  int d = blockIdx.x * 4 + w;
  if (d >= n) return;
  int base = rowptr[d], cnt = rowptr[d + 1] - base;
  const int* sp = csr_src + base;
  int h8 = l & 7;
  float adst8 = a_dst1[(size_t)d * 8 + h8];
  float p = 0.f;
  for (int i = l >> 3; i < cnt; i += 8) {
    float e = a_src1[(size_t)sp[i] * 8 + h8] + adst8;
    e = LEAKY(e);
    p += __expf(e);
  }
  p += __shfl_xor(p, 8, 64);
  p += __shfl_xor(p, 16, 64);
  p += __shfl_xor(p, 32, 64);
  float rinv = 1.f / (p + 1e-16f);  // valid for head l&7 on every lane
  int hh = l >> 3;                  // head of owned channels
  float rh = __shfl(rinv, hh, 64);  // lane hh holds head hh
  float adst = __shfl(adst8, hh, 64);
  float4 acc = make_float4(0.f, 0.f, 0.f, 0.f);
  int i = 0;
  for (; i + 8 <= cnt; i += 8) {
    int s[8];
    H4 v[8];
    float xv[8];
#pragma unroll
    for (int j = 0; j < 8; j++) s[j] = sp[i + j];
#pragma unroll
    for (int j = 0; j < 8; j++)
      v[j] = *(const H4*)(h1h + (size_t)s[j] * 256 + 4 * l);
#pragma unroll
    for (int j = 0; j < 8; j++) {
      float e = a_src1[(size_t)s[j] * 8 + hh] + adst;
      e = LEAKY(e);
      xv[j] = __expf(e) * rh;
    }
#pragma unroll
    for (int j = 0; j < 8; j++) {
      float2 p0 = __half22float2(v[j].a), p1 = __half22float2(v[j].b);
      acc.x = fmaf(p0.x, xv[j], acc.x);
      acc.y = fmaf(p0.y, xv[j], acc.y);
      acc.z = fmaf(p1.x, xv[j], acc.z);
      acc.w = fmaf(p1.y, xv[j], acc.w);
    }
  }
  for (; i < cnt; i++) {
    int s = sp[i];
    float e = a_src1[(size_t)s * 8 + hh] + adst;
    e = LEAKY(e);
    float a = __expf(e) * rh;
    H4 v = *(const H4*)(h1h + (size_t)s * 256 + 4 * l);
    float2 p0 = __half22float2(v.a), p1 = __half22float2(v.b);
    acc.x = fmaf(p0.x, a, acc.x);
    acc.y = fmaf(p0.y, a, acc.y);
    acc.z = fmaf(p1.x, a, acc.z);
    acc.w = fmaf(p1.y, a, acc.w);
  }
  float4 b = *(const float4*)(bias + 4 * l);
  float4 o;
  o.x = acc.x + b.x;
  o.y = acc.y + b.y;
  o.z = acc.z + b.z;
  o.w = acc.w + b.w;
  o.x = o.x > 0.f ? o.x : expm1f(o.x);
  o.y = o.y > 0.f ? o.y : expm1f(o.y);
  o.z = o.z > 0.f ? o.z : expm1f(o.z);
  o.w = o.w > 0.f ? o.w : expm1f(o.w);
  *(float4*)(h_act + (size_t)d * 256 + 4 * l) = o;
}

// ------- layer-2 aggregation: wave per dst, logits recomputed --------------
__global__ __launch_bounds__(256) void agg2_kernel(
    const int* __restrict__ rowptr, const int* __restrict__ csr_src,
    const float* __restrict__ a_src2, const float* __restrict__ a_dst2,
    const __half* __restrict__ h2h, const float* __restrict__ bias,
    float* __restrict__ out, int n) {
  int w = threadIdx.x >> 6, l = threadIdx.x & 63;
  int d = blockIdx.x * 4 + w;
  if (d >= n) return;
  int base = rowptr[d], cnt = rowptr[d + 1] - base;
  const int* sp = csr_src + base;
  float adst = a_dst2[d];
  float p = 0.f;
  for (int i = l; i < cnt; i += 64) {
    float e = a_src2[sp[i]] + adst;
    e = LEAKY(e);
    p += __expf(e);
  }
#pragma unroll
  for (int o = 32; o; o >>= 1) p += __shfl_xor(p, o, 64);
  float rinv = 1.f / (p + 1e-16f);
  int e2 = l >> 5;           // edge slot 0/1
  int c2 = (l & 31) * 2;     // channel pair
  float2 acc = make_float2(0.f, 0.f);
  int i = 0;
  for (; i + 16 <= cnt; i += 16) {
    int s[8];
    __half2 v[8];
    float xv[8];
#pragma unroll
    for (int j = 0; j < 8; j++) s[j] = sp[i + j * 2 + e2];
#pragma unroll
    for (int j = 0; j < 8; j++)
      v[j] = *(const __half2*)(h2h + (size_t)s[j] * 64 + c2);
#pragma unroll
    for (int j = 0; j < 8; j++) {
      float e = a_src2[s[j]] + adst;
      e = LEAKY(e);
      xv[j] = __expf(e) * rinv;
    }
#pragma unroll
    for (int j = 0; j < 8; j++) {
      float2 f = __half22float2(v[j]);
      acc.x = fmaf(f.x, xv[j], acc.x);
      acc.y = fmaf(f.y, xv[j], acc.y);
    }
  }
  for (; i + e2 < cnt; i += 2) {
    int s = sp[i + e2];
    float e = a_src2[s] + adst;
    e = LEAKY(e);
    float a = __expf(e) * rinv;
    float2 f = __half22float2(*(const __half2*)(h2h + (size_t)s * 64 + c2));
    acc.x = fmaf(f.x, a, acc.x);
    acc.y = fmaf(f.y, a, acc.y);
  }
  acc.x += __shfl_xor(acc.x, 32, 64);
  acc.y += __shfl_xor(acc.y, 32, 64);
  if (l < 32) {
    float2 b = *(const float2*)(bias + c2);
    *(float2*)(out + (size_t)d * 64 + c2) = make_float2(acc.x + b.x, acc.y + b.y);
  }
}

// ---------------------------------------------------------------------------
extern "C" void kernel_launch(void* const* d_in, const int* in_sizes, int n_in,
                              void* d_out, int out_size, void* d_ws, size_t ws_size,
                              hipStream_t stream) {
  const float* x        = (const float*)d_in[0];
  const int*   ei       = (const int*)d_in[1];
  const float* W1       = (const float*)d_in[3];
  const float* att_src1 = (const float*)d_in[4];
  const float* att_dst1 = (const float*)d_in[5];
  const float* bias1    = (const float*)d_in[6];
  const float* W2       = (const float*)d_in[7];
  const float* att_src2 = (const float*)d_in[8];
  const float* att_dst2 = (const float*)d_in[9];
  const float* bias2    = (const float*)d_in[10];
  float* out = (float*)d_out;

  int N = in_sizes[0] / 128;
  int E = in_sizes[1] / 2;
  int Etot = E + N;
  int nb = (N + 255) / 256;

  char* ws = (char*)d_ws;
  size_t off = 0;
  auto carve = [&](size_t bytes) -> void* {
    void* p = ws + off;
    off += (bytes + 255) & ~(size_t)255;
    return p;
  };
  __half* h1h   = (__half*)carve((size_t)N * 256 * 2);  // [N][256]
  __half* h2h   = (__half*)carve((size_t)N * 64 * 2);   // [N][64]
  float* h_act  = (float*)carve((size_t)N * 256 * 4);
  float* a_src1 = (float*)carve((size_t)N * 8 * 4);     // [N][8]
  float* a_dst1 = (float*)carve((size_t)N * 8 * 4);
  float* a_src2 = (float*)carve((size_t)N * 4);
  float* a_dst2 = (float*)carve((size_t)N * 4);
  int* rowptr   = (int*)carve((size_t)(N + 1) * 4);
  int* cursor   = (int*)carve((size_t)N * 4);
  int* deg      = (int*)carve((size_t)N * 4);
  int* bsum     = (int*)carve((size_t)nb * 4);
  int* csr_src  = (int*)carve((size_t)Etot * 4);
  (void)ws_size; (void)n_in; (void)out_size;

  hipMemsetAsync(deg, 0, (size_t)N * 4, stream);
  // layer-1 projection + fused attention coefficients
  {
    dim3 g((N + 127) / 128, 4);
    gemm_att_kernel<128, 256><<<g, 256, 0, stream>>>(
        x, W1, h1h, att_src1, att_dst1, a_src1, a_dst1, N);
  }
  // CSR build
  hist_kernel<<<(Etot + 255) / 256, 256, 0, stream>>>(ei, E, N, deg);
  scan1_kernel<<<nb, 256, 0, stream>>>(deg, bsum, N);
  scan2_kernel<<<1, 1024, 0, stream>>>(bsum, nb);
  scan3_kernel<<<nb, 256, 0, stream>>>(deg, bsum, rowptr, cursor, N);
  scatter_kernel<<<(Etot + 255) / 256, 256, 0, stream>>>(ei, E, N, cursor, csr_src);
  // layer-1 aggregation (+bias+ELU)
  agg1_kernel<<<(N + 3) / 4, 256, 0, stream>>>(rowptr, csr_src, a_src1, a_dst1,
                                               h1h, bias1, h_act, N);
  // layer-2 projection + fused attention coefficients
  {
    dim3 g((N + 127) / 128, 1);
    gemm_att_kernel<256, 64><<<g, 256, 0, stream>>>(
        h_act, W2, h2h, att_src2, att_dst2, a_src2, a_dst2, N);
  }
  agg2_kernel<<<(N + 3) / 4, 256, 0, stream>>>(rowptr, csr_src, a_src2, a_dst2,
                                               h2h, bias2, out, N);
}

// Round 7
// 358.189 us; speedup vs baseline: 2.1054x; 1.1104x over previous
//
#include <hip/hip_runtime.h>
#include <hip/hip_bf16.h>
#include <hip/hip_fp16.h>
#include <math.h>

// ---------------------------------------------------------------------------
// 2-layer GAT on MI355X (gfx950).
// L1: in=128, H=8, C=32 (concat->256) +bias1, ELU.  L2: in=256, H=1, C=64 +bias2.
// R7: GEMMs moved to MFMA f16 (16x16x32), fragments loaded direct from global
// (A row-major fp16, B pre-transposed fp16 Bt[n][k]); att-coefficient epilogue
// kept fused on fp32 accumulators. prep mega-kernel: x->fp16 + W transposes +
// histogram. h_act stored fp16 (agg1 write traffic halved, gemm2 reads fp16).
// Aggregation kernels unchanged from R6 (in-kernel logit recompute).
// ---------------------------------------------------------------------------

#define LEAKY(e) ((e) > 0.f ? (e) : 0.2f * (e))

struct __align__(8) H4 { __half2 a, b; };  // 4 halves

typedef _Float16 half8 __attribute__((ext_vector_type(8)));
typedef float f32x4 __attribute__((ext_vector_type(4)));

// ------- MFMA GEMM + fused attention coefficients --------------------------
// C[n,NTOT] = A[n,K] @ B[K,NTOT]; A fp16 row-major, Bt fp16 [NTOT][K].
// Block: 256 thr = 4 waves; block tile 128x64; wave tile 32x64 (2x4 MFMA).
// Epilogue: fp16 C store + per-row att_src/att_dst dots (fp32 acc),
// shuffle-reduced over the 16 col-lanes. NTOT=256: per-head (32-col) sums.
template <int K, int NTOT>
__global__ __launch_bounds__(256) void gemm_mfma_kernel(
    const _Float16* __restrict__ Ah, const _Float16* __restrict__ Bt,
    _Float16* __restrict__ Ch, const float* __restrict__ att_src,
    const float* __restrict__ att_dst, float* __restrict__ a_src,
    float* __restrict__ a_dst, int n) {
  int t = threadIdx.x;
  int w = t >> 6, l = t & 63;
  int lm = l & 15, lq = l >> 4;
  int m0 = blockIdx.x * 128 + w * 32;
  int c0 = blockIdx.y * 64;
  int ra = m0 + lm;      if (ra > n - 1) ra = n - 1;
  int rb = m0 + 16 + lm; if (rb > n - 1) rb = n - 1;
  f32x4 acc[2][4];
#pragma unroll
  for (int mt = 0; mt < 2; mt++)
#pragma unroll
    for (int nt = 0; nt < 4; nt++) acc[mt][nt] = (f32x4){0.f, 0.f, 0.f, 0.f};
  for (int k0 = 0; k0 < K; k0 += 32) {
    half8 a0 = *(const half8*)(Ah + (size_t)ra * K + k0 + lq * 8);
    half8 a1 = *(const half8*)(Ah + (size_t)rb * K + k0 + lq * 8);
    half8 b0 = *(const half8*)(Bt + (size_t)(c0 + 0 + lm) * K + k0 + lq * 8);
    half8 b1 = *(const half8*)(Bt + (size_t)(c0 + 16 + lm) * K + k0 + lq * 8);
    half8 b2 = *(const half8*)(Bt + (size_t)(c0 + 32 + lm) * K + k0 + lq * 8);
    half8 b3 = *(const half8*)(Bt + (size_t)(c0 + 48 + lm) * K + k0 + lq * 8);
    acc[0][0] = __builtin_amdgcn_mfma_f32_16x16x32_f16(a0, b0, acc[0][0], 0, 0, 0);
    acc[0][1] = __builtin_amdgcn_mfma_f32_16x16x32_f16(a0, b1, acc[0][1], 0, 0, 0);
    acc[0][2] = __builtin_amdgcn_mfma_f32_16x16x32_f16(a0, b2, acc[0][2], 0, 0, 0);
    acc[0][3] = __builtin_amdgcn_mfma_f32_16x16x32_f16(a0, b3, acc[0][3], 0, 0, 0);
    acc[1][0] = __builtin_amdgcn_mfma_f32_16x16x32_f16(a1, b0, acc[1][0], 0, 0, 0);
    acc[1][1] = __builtin_amdgcn_mfma_f32_16x16x32_f16(a1, b1, acc[1][1], 0, 0, 0);
    acc[1][2] = __builtin_amdgcn_mfma_f32_16x16x32_f16(a1, b2, acc[1][2], 0, 0, 0);
    acc[1][3] = __builtin_amdgcn_mfma_f32_16x16x32_f16(a1, b3, acc[1][3], 0, 0, 0);
  }
  float as_[4], ad_[4];
#pragma unroll
  for (int nt = 0; nt < 4; nt++) {
    as_[nt] = att_src[c0 + nt * 16 + lm];
    ad_[nt] = att_dst[c0 + nt * 16 + lm];
  }
#pragma unroll
  for (int mt = 0; mt < 2; mt++) {
#pragma unroll
    for (int i = 0; i < 4; i++) {
      int gr = m0 + mt * 16 + lq * 4 + i;
      bool ok = gr < n;
      if (ok) {
#pragma unroll
        for (int nt = 0; nt < 4; nt++)
          Ch[(size_t)gr * NTOT + c0 + nt * 16 + lm] = (_Float16)acc[mt][nt][i];
      }
      float p0 = acc[mt][0][i] * as_[0] + acc[mt][1][i] * as_[1];
      float p1 = acc[mt][2][i] * as_[2] + acc[mt][3][i] * as_[3];
      float q0 = acc[mt][0][i] * ad_[0] + acc[mt][1][i] * ad_[1];
      float q1 = acc[mt][2][i] * ad_[2] + acc[mt][3][i] * ad_[3];
#pragma unroll
      for (int o = 1; o < 16; o <<= 1) {
        p0 += __shfl_xor(p0, o, 64);
        p1 += __shfl_xor(p1, o, 64);
        q0 += __shfl_xor(q0, o, 64);
        q1 += __shfl_xor(q1, o, 64);
      }
      if (lm == 0 && ok) {
        if (NTOT == 256) {
          int h0 = c0 >> 5;
          a_src[(size_t)gr * 8 + h0] = p0;
          a_src[(size_t)gr * 8 + h0 + 1] = p1;
          a_dst[(size_t)gr * 8 + h0] = q0;
          a_dst[(size_t)gr * 8 + h0 + 1] = q1;
        } else {
          a_src[gr] = p0 + p1;
          a_dst[gr] = q0 + q1;
        }
      }
    }
  }
}

// ------- prep: x->fp16, W1/W2 transpose->fp16, degree histogram ------------
__global__ __launch_bounds__(256) void prep_kernel(
    const float* __restrict__ x, const float* __restrict__ W1,
    const float* __restrict__ W2, const int* __restrict__ ei,
    _Float16* __restrict__ xh, _Float16* __restrict__ Bt1,
    _Float16* __restrict__ Bt2, int* __restrict__ deg, int N, int E) {
  int t = threadIdx.x;
  int b = blockIdx.x;
  int nbx = (N * 128 / 8 + 255) / 256;
  const int nbw1 = 128;  // 32768/256
  const int nbw2 = 64;   // 16384/256
  if (b < nbx) {
    int i8 = (b * 256 + t) * 8;
    if (i8 < N * 128) {
      float4 v0 = *(const float4*)(x + i8);
      float4 v1 = *(const float4*)(x + i8 + 4);
      half8 h;
      h[0] = (_Float16)v0.x; h[1] = (_Float16)v0.y;
      h[2] = (_Float16)v0.z; h[3] = (_Float16)v0.w;
      h[4] = (_Float16)v1.x; h[5] = (_Float16)v1.y;
      h[6] = (_Float16)v1.z; h[7] = (_Float16)v1.w;
      *(half8*)(xh + i8) = h;
    }
  } else if (b < nbx + nbw1) {
    int o = (b - nbx) * 256 + t;        // o = n*128 + k
    int nn = o >> 7, kk = o & 127;
    Bt1[o] = (_Float16)W1[kk * 256 + nn];
  } else if (b < nbx + nbw1 + nbw2) {
    int o = (b - nbx - nbw1) * 256 + t; // o = n*256 + k
    int nn = o >> 8, kk = o & 255;
    Bt2[o] = (_Float16)W2[kk * 64 + nn];
  } else {
    int idx = (b - nbx - nbw1 - nbw2) * 256 + t;
    if (idx < E + N) {
      int d = (idx < E) ? ei[E + idx] : (idx - E);
      atomicAdd(&deg[d], 1);
    }
  }
}

// ------------------------- CSR scan + scatter ------------------------------
__global__ __launch_bounds__(256) void scan1_kernel(
    const int* __restrict__ deg, int* __restrict__ bsum, int n) {
  __shared__ int ws[4];
  int t = threadIdx.x;
  int i = blockIdx.x * 256 + t;
  int v = (i < n) ? deg[i] : 0;
  int wv = v;
#pragma unroll
  for (int o = 32; o; o >>= 1) wv += __shfl_xor(wv, o, 64);
  if ((t & 63) == 0) ws[t >> 6] = wv;
  __syncthreads();
  if (t == 0) bsum[blockIdx.x] = ws[0] + ws[1] + ws[2] + ws[3];
}

__global__ __launch_bounds__(1024) void scan2_kernel(int* __restrict__ bsum,
                                                     int nb) {
  __shared__ int sb[1024];
  int t = threadIdx.x;
  int v = (t < nb) ? bsum[t] : 0;
  sb[t] = v;
  __syncthreads();
  int x = v;
  for (int off = 1; off < 1024; off <<= 1) {
    int y = (t >= off) ? sb[t - off] : 0;
    __syncthreads();
    x += y;
    sb[t] = x;
    __syncthreads();
  }
  if (t < nb) bsum[t] = x - v;  // exclusive
}

__global__ __launch_bounds__(256) void scan3_kernel(
    const int* __restrict__ deg, const int* __restrict__ bsum,
    int* __restrict__ rowptr, int* __restrict__ cursor, int n) {
  __shared__ int sb[256];
  int t = threadIdx.x;
  int i = blockIdx.x * 256 + t;
  int v = (i < n) ? deg[i] : 0;
  sb[t] = v;
  __syncthreads();
  int x = v;
  for (int off = 1; off < 256; off <<= 1) {
    int y = (t >= off) ? sb[t - off] : 0;
    __syncthreads();
    x += y;
    sb[t] = x;
    __syncthreads();
  }
  int excl = x - v + bsum[blockIdx.x];
  if (i < n) {
    rowptr[i] = excl;
    cursor[i] = excl;
  }
  if (i == n - 1) rowptr[n] = excl + v;
}

__global__ __launch_bounds__(256) void scatter_kernel(
    const int* __restrict__ ei, int E, int n, int* __restrict__ cursor,
    int* __restrict__ csr_src) {
  int idx = blockIdx.x * 256 + threadIdx.x;
  if (idx >= E + n) return;
  int s, d;
  if (idx < E) {
    s = ei[idx];
    d = ei[E + idx];
  } else {
    s = d = idx - E;
  }
  int pos = atomicAdd(&cursor[d], 1);
  csr_src[pos] = s;
}

// ------- layer-1 aggregation: one wave per dst; logits recomputed ----------
__global__ __launch_bounds__(256) void agg1_kernel(
    const int* __restrict__ rowptr, const int* __restrict__ csr_src,
    const float* __restrict__ a_src1, const float* __restrict__ a_dst1,
    const __half* __restrict__ h1h, const float* __restrict__ bias,
    _Float16* __restrict__ h_act, int n) {
  int w = threadIdx.x >> 6, l = threadIdx.x & 63;
  int d = blockIdx.x * 4 + w;
  if (d >= n) return;
  int base = rowptr[d], cnt = rowptr[d + 1] - base;
  const int* sp = csr_src + base;
  int h8 = l & 7;
  float adst8 = a_dst1[(size_t)d * 8 + h8];
  float p = 0.f;
  for (int i = l >> 3; i < cnt; i += 8) {
    float e = a_src1[(size_t)sp[i] * 8 + h8] + adst8;
    e = LEAKY(e);
    p += __expf(e);
  }
  p += __shfl_xor(p, 8, 64);
  p += __shfl_xor(p, 16, 64);
  p += __shfl_xor(p, 32, 64);
  float rinv = 1.f / (p + 1e-16f);
  int hh = l >> 3;
  float rh = __shfl(rinv, hh, 64);
  float adst = __shfl(adst8, hh, 64);
  float4 acc = make_float4(0.f, 0.f, 0.f, 0.f);
  int i = 0;
  for (; i + 8 <= cnt; i += 8) {
    int s[8];
    H4 v[8];
    float xv[8];
#pragma unroll
    for (int j = 0; j < 8; j++) s[j] = sp[i + j];
#pragma unroll
    for (int j = 0; j < 8; j++)
      v[j] = *(const H4*)(h1h + (size_t)s[j] * 256 + 4 * l);
#pragma unroll
    for (int j = 0; j < 8; j++) {
      float e = a_src1[(size_t)s[j] * 8 + hh] + adst;
      e = LEAKY(e);
      xv[j] = __expf(e) * rh;
    }
#pragma unroll
    for (int j = 0; j < 8; j++) {
      float2 p0 = __half22float2(v[j].a), p1 = __half22float2(v[j].b);
      acc.x = fmaf(p0.x, xv[j], acc.x);
      acc.y = fmaf(p0.y, xv[j], acc.y);
      acc.z = fmaf(p1.x, xv[j], acc.z);
      acc.w = fmaf(p1.y, xv[j], acc.w);
    }
  }
  for (; i < cnt; i++) {
    int s = sp[i];
    float e = a_src1[(size_t)s * 8 + hh] + adst;
    e = LEAKY(e);
    float a = __expf(e) * rh;
    H4 v = *(const H4*)(h1h + (size_t)s * 256 + 4 * l);
    float2 p0 = __half22float2(v.a), p1 = __half22float2(v.b);
    acc.x = fmaf(p0.x, a, acc.x);
    acc.y = fmaf(p0.y, a, acc.y);
    acc.z = fmaf(p1.x, a, acc.z);
    acc.w = fmaf(p1.y, a, acc.w);
  }
  float4 b = *(const float4*)(bias + 4 * l);
  float ox = acc.x + b.x, oy = acc.y + b.y, oz = acc.z + b.z, ow = acc.w + b.w;
  ox = ox > 0.f ? ox : expm1f(ox);
  oy = oy > 0.f ? oy : expm1f(oy);
  oz = oz > 0.f ? oz : expm1f(oz);
  ow = ow > 0.f ? ow : expm1f(ow);
  half8* dummy;  // silence unused-typedef style warnings (no-op)
  (void)dummy;
  H4 hv;
  hv.a = __floats2half2_rn(ox, oy);
  hv.b = __floats2half2_rn(oz, ow);
  *(H4*)(h_act + (size_t)d * 256 + 4 * l) = hv;
}

// ------- layer-2 aggregation: wave per dst, logits recomputed --------------
__global__ __launch_bounds__(256) void agg2_kernel(
    const int* __restrict__ rowptr, const int* __restrict__ csr_src,
    const float* __restrict__ a_src2, const float* __restrict__ a_dst2,
    const __half* __restrict__ h2h, const float* __restrict__ bias,
    float* __restrict__ out, int n) {
  int w = threadIdx.x >> 6, l = threadIdx.x & 63;
  int d = blockIdx.x * 4 + w;
  if (d >= n) return;
  int base = rowptr[d], cnt = rowptr[d + 1] - base;
  const int* sp = csr_src + base;
  float adst = a_dst2[d];
  float p = 0.f;
  for (int i = l; i < cnt; i += 64) {
    float e = a_src2[sp[i]] + adst;
    e = LEAKY(e);
    p += __expf(e);
  }
#pragma unroll
  for (int o = 32; o; o >>= 1) p += __shfl_xor(p, o, 64);
  float rinv = 1.f / (p + 1e-16f);
  int e2 = l >> 5;
  int c2 = (l & 31) * 2;
  float2 acc = make_float2(0.f, 0.f);
  int i = 0;
  for (; i + 16 <= cnt; i += 16) {
    int s[8];
    __half2 v[8];
    float xv[8];
#pragma unroll
    for (int j = 0; j < 8; j++) s[j] = sp[i + j * 2 + e2];
#pragma unroll
    for (int j = 0; j < 8; j++)
      v[j] = *(const __half2*)(h2h + (size_t)s[j] * 64 + c2);
#pragma unroll
    for (int j = 0; j < 8; j++) {
      float e = a_src2[s[j]] + adst;
      e = LEAKY(e);
      xv[j] = __expf(e) * rinv;
    }
#pragma unroll
    for (int j = 0; j < 8; j++) {
      float2 f = __half22float2(v[j]);
      acc.x = fmaf(f.x, xv[j], acc.x);
      acc.y = fmaf(f.y, xv[j], acc.y);
    }
  }
  for (; i + e2 < cnt; i += 2) {
    int s = sp[i + e2];
    float e = a_src2[s] + adst;
    e = LEAKY(e);
    float a = __expf(e) * rinv;
    float2 f = __half22float2(*(const __half2*)(h2h + (size_t)s * 64 + c2));
    acc.x = fmaf(f.x, a, acc.x);
    acc.y = fmaf(f.y, a, acc.y);
  }
  acc.x += __shfl_xor(acc.x, 32, 64);
  acc.y += __shfl_xor(acc.y, 32, 64);
  if (l < 32) {
    float2 b = *(const float2*)(bias + c2);
    *(float2*)(out + (size_t)d * 64 + c2) = make_float2(acc.x + b.x, acc.y + b.y);
  }
}

// ---------------------------------------------------------------------------
extern "C" void kernel_launch(void* const* d_in, const int* in_sizes, int n_in,
                              void* d_out, int out_size, void* d_ws, size_t ws_size,
                              hipStream_t stream) {
  const float* x        = (const float*)d_in[0];
  const int*   ei       = (const int*)d_in[1];
  const float* W1       = (const float*)d_in[3];
  const float* att_src1 = (const float*)d_in[4];
  const float* att_dst1 = (const float*)d_in[5];
  const float* bias1    = (const float*)d_in[6];
  const float* W2       = (const float*)d_in[7];
  const float* att_src2 = (const float*)d_in[8];
  const float* att_dst2 = (const float*)d_in[9];
  const float* bias2    = (const float*)d_in[10];
  float* out = (float*)d_out;

  int N = in_sizes[0] / 128;
  int E = in_sizes[1] / 2;
  int Etot = E + N;
  int nb = (N + 255) / 256;

  char* ws = (char*)d_ws;
  size_t off = 0;
  auto carve = [&](size_t bytes) -> void* {
    void* p = ws + off;
    off += (bytes + 255) & ~(size_t)255;
    return p;
  };
  _Float16* xh   = (_Float16*)carve((size_t)N * 128 * 2);
  _Float16* Bt1  = (_Float16*)carve((size_t)256 * 128 * 2);
  _Float16* Bt2  = (_Float16*)carve((size_t)64 * 256 * 2);
  _Float16* h1h  = (_Float16*)carve((size_t)N * 256 * 2);
  _Float16* h2h  = (_Float16*)carve((size_t)N * 64 * 2);
  _Float16* h_act= (_Float16*)carve((size_t)N * 256 * 2);
  float* a_src1 = (float*)carve((size_t)N * 8 * 4);
  float* a_dst1 = (float*)carve((size_t)N * 8 * 4);
  float* a_src2 = (float*)carve((size_t)N * 4);
  float* a_dst2 = (float*)carve((size_t)N * 4);
  int* rowptr   = (int*)carve((size_t)(N + 1) * 4);
  int* cursor   = (int*)carve((size_t)N * 4);
  int* deg      = (int*)carve((size_t)N * 4);
  int* bsum     = (int*)carve((size_t)nb * 4);
  int* csr_src  = (int*)carve((size_t)Etot * 4);
  (void)ws_size; (void)n_in; (void)out_size;

  hipMemsetAsync(deg, 0, (size_t)N * 4, stream);
  // prep: x->fp16, W transposes, histogram
  {
    int nbx = (N * 128 / 8 + 255) / 256;
    int grid = nbx + 128 + 64 + (Etot + 255) / 256;
    prep_kernel<<<grid, 256, 0, stream>>>(x, W1, W2, ei, xh, Bt1, Bt2, deg, N, E);
  }
  // layer-1 projection (MFMA) + fused attention coefficients
  {
    dim3 g((N + 127) / 128, 4);
    gemm_mfma_kernel<128, 256><<<g, 256, 0, stream>>>(
        xh, Bt1, h1h, att_src1, att_dst1, a_src1, a_dst1, N);
  }
  // CSR build
  scan1_kernel<<<nb, 256, 0, stream>>>(deg, bsum, N);
  scan2_kernel<<<1, 1024, 0, stream>>>(bsum, nb);
  scan3_kernel<<<nb, 256, 0, stream>>>(deg, bsum, rowptr, cursor, N);
  scatter_kernel<<<(Etot + 255) / 256, 256, 0, stream>>>(ei, E, N, cursor, csr_src);
  // layer-1 aggregation (+bias+ELU, fp16 out)
  agg1_kernel<<<(N + 3) / 4, 256, 0, stream>>>(rowptr, csr_src, a_src1, a_dst1,
                                               (const __half*)h1h, bias1, h_act, N);
  // layer-2 projection (MFMA) + fused attention coefficients
  {
    dim3 g((N + 127) / 128, 1);
    gemm_mfma_kernel<256, 64><<<g, 256, 0, stream>>>(
        h_act, Bt2, h2h, att_src2, att_dst2, a_src2, a_dst2, N);
  }
  agg2_kernel<<<(N + 3) / 4, 256, 0, stream>>>(rowptr, csr_src, a_src2, a_dst2,
                                               (const __half*)h2h, bias2, out, N);
}

// Round 8
// 338.864 us; speedup vs baseline: 2.2255x; 1.0570x over previous
//
#include <hip/hip_runtime.h>
#include <hip/hip_bf16.h>
#include <hip/hip_fp16.h>
#include <math.h>

// ---------------------------------------------------------------------------
// 2-layer GAT on MI355X (gfx950).
// L1: in=128, H=8, C=32 (concat->256) +bias1, ELU.  L2: in=256, H=1, C=64 +bias2.
// R8: single-pass softmax-aggregate (normalize at end; no max-subtraction is
// exact for these logit magnitudes), gemm1 converts x fp32->fp16 in-register
// (xh array deleted), scan 3->2 kernels (per-block bsum reduce). 9 dispatches.
// ---------------------------------------------------------------------------

#define LEAKY(e) ((e) > 0.f ? (e) : 0.2f * (e))

struct __align__(8) H4 { __half2 a, b; };  // 4 halves

typedef _Float16 half8 __attribute__((ext_vector_type(8)));
typedef float f32x4 __attribute__((ext_vector_type(4)));

// ------- MFMA GEMM + fused attention coefficients --------------------------
// C[n,NTOT] = A[n,K] @ B[K,NTOT]; A row-major (fp32 if AF32 else fp16),
// Bt fp16 [NTOT][K]. Block: 4 waves; block tile 128x64; wave tile 32x64.
template <int K, int NTOT, bool AF32>
__global__ __launch_bounds__(256) void gemm_mfma_kernel(
    const void* __restrict__ Av, const _Float16* __restrict__ Bt,
    _Float16* __restrict__ Ch, const float* __restrict__ att_src,
    const float* __restrict__ att_dst, float* __restrict__ a_src,
    float* __restrict__ a_dst, int n) {
  int t = threadIdx.x;
  int w = t >> 6, l = t & 63;
  int lm = l & 15, lq = l >> 4;
  int m0 = blockIdx.x * 128 + w * 32;
  int c0 = blockIdx.y * 64;
  int ra = m0 + lm;      if (ra > n - 1) ra = n - 1;
  int rb = m0 + 16 + lm; if (rb > n - 1) rb = n - 1;
  f32x4 acc[2][4];
#pragma unroll
  for (int mt = 0; mt < 2; mt++)
#pragma unroll
    for (int nt = 0; nt < 4; nt++) acc[mt][nt] = (f32x4){0.f, 0.f, 0.f, 0.f};
  for (int k0 = 0; k0 < K; k0 += 32) {
    half8 a0, a1;
    if (AF32) {
      const float* pa = (const float*)Av + (size_t)ra * K + k0 + lq * 8;
      const float* pb = (const float*)Av + (size_t)rb * K + k0 + lq * 8;
      float4 u0 = *(const float4*)pa, u1 = *(const float4*)(pa + 4);
      float4 w0 = *(const float4*)pb, w1 = *(const float4*)(pb + 4);
      a0[0] = (_Float16)u0.x; a0[1] = (_Float16)u0.y;
      a0[2] = (_Float16)u0.z; a0[3] = (_Float16)u0.w;
      a0[4] = (_Float16)u1.x; a0[5] = (_Float16)u1.y;
      a0[6] = (_Float16)u1.z; a0[7] = (_Float16)u1.w;
      a1[0] = (_Float16)w0.x; a1[1] = (_Float16)w0.y;
      a1[2] = (_Float16)w0.z; a1[3] = (_Float16)w0.w;
      a1[4] = (_Float16)w1.x; a1[5] = (_Float16)w1.y;
      a1[6] = (_Float16)w1.z; a1[7] = (_Float16)w1.w;
    } else {
      a0 = *(const half8*)((const _Float16*)Av + (size_t)ra * K + k0 + lq * 8);
      a1 = *(const half8*)((const _Float16*)Av + (size_t)rb * K + k0 + lq * 8);
    }
    half8 b0 = *(const half8*)(Bt + (size_t)(c0 + 0 + lm) * K + k0 + lq * 8);
    half8 b1 = *(const half8*)(Bt + (size_t)(c0 + 16 + lm) * K + k0 + lq * 8);
    half8 b2 = *(const half8*)(Bt + (size_t)(c0 + 32 + lm) * K + k0 + lq * 8);
    half8 b3 = *(const half8*)(Bt + (size_t)(c0 + 48 + lm) * K + k0 + lq * 8);
    acc[0][0] = __builtin_amdgcn_mfma_f32_16x16x32_f16(a0, b0, acc[0][0], 0, 0, 0);
    acc[0][1] = __builtin_amdgcn_mfma_f32_16x16x32_f16(a0, b1, acc[0][1], 0, 0, 0);
    acc[0][2] = __builtin_amdgcn_mfma_f32_16x16x32_f16(a0, b2, acc[0][2], 0, 0, 0);
    acc[0][3] = __builtin_amdgcn_mfma_f32_16x16x32_f16(a0, b3, acc[0][3], 0, 0, 0);
    acc[1][0] = __builtin_amdgcn_mfma_f32_16x16x32_f16(a1, b0, acc[1][0], 0, 0, 0);
    acc[1][1] = __builtin_amdgcn_mfma_f32_16x16x32_f16(a1, b1, acc[1][1], 0, 0, 0);
    acc[1][2] = __builtin_amdgcn_mfma_f32_16x16x32_f16(a1, b2, acc[1][2], 0, 0, 0);
    acc[1][3] = __builtin_amdgcn_mfma_f32_16x16x32_f16(a1, b3, acc[1][3], 0, 0, 0);
  }
  float as_[4], ad_[4];
#pragma unroll
  for (int nt = 0; nt < 4; nt++) {
    as_[nt] = att_src[c0 + nt * 16 + lm];
    ad_[nt] = att_dst[c0 + nt * 16 + lm];
  }
#pragma unroll
  for (int mt = 0; mt < 2; mt++) {
#pragma unroll
    for (int i = 0; i < 4; i++) {
      int gr = m0 + mt * 16 + lq * 4 + i;
      bool ok = gr < n;
      if (ok) {
#pragma unroll
        for (int nt = 0; nt < 4; nt++)
          Ch[(size_t)gr * NTOT + c0 + nt * 16 + lm] = (_Float16)acc[mt][nt][i];
      }
      float p0 = acc[mt][0][i] * as_[0] + acc[mt][1][i] * as_[1];
      float p1 = acc[mt][2][i] * as_[2] + acc[mt][3][i] * as_[3];
      float q0 = acc[mt][0][i] * ad_[0] + acc[mt][1][i] * ad_[1];
      float q1 = acc[mt][2][i] * ad_[2] + acc[mt][3][i] * ad_[3];
#pragma unroll
      for (int o = 1; o < 16; o <<= 1) {
        p0 += __shfl_xor(p0, o, 64);
        p1 += __shfl_xor(p1, o, 64);
        q0 += __shfl_xor(q0, o, 64);
        q1 += __shfl_xor(q1, o, 64);
      }
      if (lm == 0 && ok) {
        if (NTOT == 256) {
          int h0 = c0 >> 5;
          a_src[(size_t)gr * 8 + h0] = p0;
          a_src[(size_t)gr * 8 + h0 + 1] = p1;
          a_dst[(size_t)gr * 8 + h0] = q0;
          a_dst[(size_t)gr * 8 + h0 + 1] = q1;
        } else {
          a_src[gr] = p0 + p1;
          a_dst[gr] = q0 + q1;
        }
      }
    }
  }
}

// ------- prep: W1/W2 transpose->fp16, degree histogram ---------------------
__global__ __launch_bounds__(256) void prep_kernel(
    const float* __restrict__ W1, const float* __restrict__ W2,
    const int* __restrict__ ei, _Float16* __restrict__ Bt1,
    _Float16* __restrict__ Bt2, int* __restrict__ deg, int N, int E) {
  int t = threadIdx.x;
  int b = blockIdx.x;
  const int nbw1 = 128;  // 32768/256
  const int nbw2 = 64;   // 16384/256
  if (b < nbw1) {
    int o = b * 256 + t;        // o = n*128 + k
    int nn = o >> 7, kk = o & 127;
    Bt1[o] = (_Float16)W1[kk * 256 + nn];
  } else if (b < nbw1 + nbw2) {
    int o = (b - nbw1) * 256 + t;  // o = n*256 + k
    int nn = o >> 8, kk = o & 255;
    Bt2[o] = (_Float16)W2[kk * 64 + nn];
  } else {
    int idx = (b - nbw1 - nbw2) * 256 + t;
    if (idx < E + N) {
      int d = (idx < E) ? ei[E + idx] : (idx - E);
      atomicAdd(&deg[d], 1);
    }
  }
}

// ------------------------- CSR scan + scatter ------------------------------
__global__ __launch_bounds__(256) void scan1_kernel(
    const int* __restrict__ deg, int* __restrict__ bsum, int n) {
  __shared__ int ws[4];
  int t = threadIdx.x;
  int i = blockIdx.x * 256 + t;
  int v = (i < n) ? deg[i] : 0;
  int wv = v;
#pragma unroll
  for (int o = 32; o; o >>= 1) wv += __shfl_xor(wv, o, 64);
  if ((t & 63) == 0) ws[t >> 6] = wv;
  __syncthreads();
  if (t == 0) bsum[blockIdx.x] = ws[0] + ws[1] + ws[2] + ws[3];
}

// per-block: carry = sum(bsum[0..blockIdx)), then local exclusive scan.
// requires gridDim.x <= 256.
__global__ __launch_bounds__(256) void scan3_kernel(
    const int* __restrict__ deg, const int* __restrict__ bsum,
    int* __restrict__ rowptr, int* __restrict__ cursor, int n) {
  __shared__ int sb[256];
  __shared__ int ws[4];
  int t = threadIdx.x;
  int vb = (t < (int)blockIdx.x) ? bsum[t] : 0;
  int wv = vb;
#pragma unroll
  for (int o = 32; o; o >>= 1) wv += __shfl_xor(wv, o, 64);
  if ((t & 63) == 0) ws[t >> 6] = wv;
  __syncthreads();
  int carry = ws[0] + ws[1] + ws[2] + ws[3];
  int i = blockIdx.x * 256 + t;
  int v = (i < n) ? deg[i] : 0;
  sb[t] = v;
  __syncthreads();
  int x = v;
  for (int off = 1; off < 256; off <<= 1) {
    int y = (t >= off) ? sb[t - off] : 0;
    __syncthreads();
    x += y;
    sb[t] = x;
    __syncthreads();
  }
  int excl = x - v + carry;
  if (i < n) {
    rowptr[i] = excl;
    cursor[i] = excl;
  }
  if (i == n - 1) rowptr[n] = excl + v;
}

__global__ __launch_bounds__(256) void scatter_kernel(
    const int* __restrict__ ei, int E, int n, int* __restrict__ cursor,
    int* __restrict__ csr_src) {
  int idx = blockIdx.x * 256 + threadIdx.x;
  if (idx >= E + n) return;
  int s, d;
  if (idx < E) {
    s = ei[idx];
    d = ei[E + idx];
  } else {
    s = d = idx - E;
  }
  int pos = atomicAdd(&cursor[d], 1);
  csr_src[pos] = s;
}

// ------- layer-1 aggregation: one wave per dst; single-pass softmax --------
// lane l owns channels 4l..4l+3 (head l>>3); denominator accumulated inline.
__global__ __launch_bounds__(256) void agg1_kernel(
    const int* __restrict__ rowptr, const int* __restrict__ csr_src,
    const float* __restrict__ a_src1, const float* __restrict__ a_dst1,
    const __half* __restrict__ h1h, const float* __restrict__ bias,
    _Float16* __restrict__ h_act, int n) {
  int w = threadIdx.x >> 6, l = threadIdx.x & 63;
  int d = blockIdx.x * 4 + w;
  if (d >= n) return;
  int base = rowptr[d], cnt = rowptr[d + 1] - base;
  const int* sp = csr_src + base;
  int hh = l >> 3;  // head of owned channels
  float adst = a_dst1[(size_t)d * 8 + hh];
  float4 acc = make_float4(0.f, 0.f, 0.f, 0.f);
  float p = 0.f;
  int i = 0;
  for (; i + 8 <= cnt; i += 8) {
    int s[8];
    H4 v[8];
    float xv[8];
#pragma unroll
    for (int j = 0; j < 8; j++) s[j] = sp[i + j];
#pragma unroll
    for (int j = 0; j < 8; j++)
      v[j] = *(const H4*)(h1h + (size_t)s[j] * 256 + 4 * l);
#pragma unroll
    for (int j = 0; j < 8; j++) {
      float e = a_src1[(size_t)s[j] * 8 + hh] + adst;
      e = LEAKY(e);
      xv[j] = __expf(e);
      p += xv[j];
    }
#pragma unroll
    for (int j = 0; j < 8; j++) {
      float2 p0 = __half22float2(v[j].a), p1 = __half22float2(v[j].b);
      acc.x = fmaf(p0.x, xv[j], acc.x);
      acc.y = fmaf(p0.y, xv[j], acc.y);
      acc.z = fmaf(p1.x, xv[j], acc.z);
      acc.w = fmaf(p1.y, xv[j], acc.w);
    }
  }
  for (; i < cnt; i++) {
    int s = sp[i];
    float e = a_src1[(size_t)s * 8 + hh] + adst;
    e = LEAKY(e);
    float a = __expf(e);
    p += a;
    H4 v = *(const H4*)(h1h + (size_t)s * 256 + 4 * l);
    float2 p0 = __half22float2(v.a), p1 = __half22float2(v.b);
    acc.x = fmaf(p0.x, a, acc.x);
    acc.y = fmaf(p0.y, a, acc.y);
    acc.z = fmaf(p1.x, a, acc.z);
    acc.w = fmaf(p1.y, a, acc.w);
  }
  float rinv = 1.f / (p + 1e-16f);
  float4 b = *(const float4*)(bias + 4 * l);
  float ox = fmaf(acc.x, rinv, b.x), oy = fmaf(acc.y, rinv, b.y);
  float oz = fmaf(acc.z, rinv, b.z), ow = fmaf(acc.w, rinv, b.w);
  ox = ox > 0.f ? ox : expm1f(ox);
  oy = oy > 0.f ? oy : expm1f(oy);
  oz = oz > 0.f ? oz : expm1f(oz);
  ow = ow > 0.f ? ow : expm1f(ow);
  H4 hv;
  hv.a = __floats2half2_rn(ox, oy);
  hv.b = __floats2half2_rn(oz, ow);
  *(H4*)(h_act + (size_t)d * 256 + 4 * l) = hv;
}

// ------- layer-2 aggregation: wave per dst; single-pass softmax ------------
__global__ __launch_bounds__(256) void agg2_kernel(
    const int* __restrict__ rowptr, const int* __restrict__ csr_src,
    const float* __restrict__ a_src2, const float* __restrict__ a_dst2,
    const __half* __restrict__ h2h, const float* __restrict__ bias,
    float* __restrict__ out, int n) {
  int w = threadIdx.x >> 6, l = threadIdx.x & 63;
  int d = blockIdx.x * 4 + w;
  if (d >= n) return;
  int base = rowptr[d], cnt = rowptr[d + 1] - base;
  const int* sp = csr_src + base;
  float adst = a_dst2[d];
  int e2 = l >> 5;
  int c2 = (l & 31) * 2;
  float2 acc = make_float2(0.f, 0.f);
  float p = 0.f;
  int i = 0;
  for (; i + 16 <= cnt; i += 16) {
    int s[8];
    __half2 v[8];
    float xv[8];
#pragma unroll
    for (int j = 0; j < 8; j++) s[j] = sp[i + j * 2 + e2];
#pragma unroll
    for (int j = 0; j < 8; j++)
      v[j] = *(const __half2*)(h2h + (size_t)s[j] * 64 + c2);
#pragma unroll
    for (int j = 0; j < 8; j++) {
      float e = a_src2[s[j]] + adst;
      e = LEAKY(e);
      xv[j] = __expf(e);
      p += xv[j];
    }
#pragma unroll
    for (int j = 0; j < 8; j++) {
      float2 f = __half22float2(v[j]);
      acc.x = fmaf(f.x, xv[j], acc.x);
      acc.y = fmaf(f.y, xv[j], acc.y);
    }
  }
  for (; i + e2 < cnt; i += 2) {
    int s = sp[i + e2];
    float e = a_src2[s] + adst;
    e = LEAKY(e);
    float a = __expf(e);
    p += a;
    float2 f = __half22float2(*(const __half2*)(h2h + (size_t)s * 64 + c2));
    acc.x = fmaf(f.x, a, acc.x);
    acc.y = fmaf(f.y, a, acc.y);
  }
  acc.x += __shfl_xor(acc.x, 32, 64);
  acc.y += __shfl_xor(acc.y, 32, 64);
  p += __shfl_xor(p, 32, 64);
  if (l < 32) {
    float rinv = 1.f / (p + 1e-16f);
    float2 b = *(const float2*)(bias + c2);
    *(float2*)(out + (size_t)d * 64 + c2) =
        make_float2(fmaf(acc.x, rinv, b.x), fmaf(acc.y, rinv, b.y));
  }
}

// ---------------------------------------------------------------------------
extern "C" void kernel_launch(void* const* d_in, const int* in_sizes, int n_in,
                              void* d_out, int out_size, void* d_ws, size_t ws_size,
                              hipStream_t stream) {
  const float* x        = (const float*)d_in[0];
  const int*   ei       = (const int*)d_in[1];
  const float* W1       = (const float*)d_in[3];
  const float* att_src1 = (const float*)d_in[4];
  const float* att_dst1 = (const float*)d_in[5];
  const float* bias1    = (const float*)d_in[6];
  const float* W2       = (const float*)d_in[7];
  const float* att_src2 = (const float*)d_in[8];
  const float* att_dst2 = (const float*)d_in[9];
  const float* bias2    = (const float*)d_in[10];
  float* out = (float*)d_out;

  int N = in_sizes[0] / 128;
  int E = in_sizes[1] / 2;
  int Etot = E + N;
  int nb = (N + 255) / 256;  // 196 <= 256 (scan3 requirement)

  char* ws = (char*)d_ws;
  size_t off = 0;
  auto carve = [&](size_t bytes) -> void* {
    void* p = ws + off;
    off += (bytes + 255) & ~(size_t)255;
    return p;
  };
  _Float16* Bt1  = (_Float16*)carve((size_t)256 * 128 * 2);
  _Float16* Bt2  = (_Float16*)carve((size_t)64 * 256 * 2);
  _Float16* h1h  = (_Float16*)carve((size_t)N * 256 * 2);
  _Float16* h2h  = (_Float16*)carve((size_t)N * 64 * 2);
  _Float16* h_act= (_Float16*)carve((size_t)N * 256 * 2);
  float* a_src1 = (float*)carve((size_t)N * 8 * 4);
  float* a_dst1 = (float*)carve((size_t)N * 8 * 4);
  float* a_src2 = (float*)carve((size_t)N * 4);
  float* a_dst2 = (float*)carve((size_t)N * 4);
  int* rowptr   = (int*)carve((size_t)(N + 1) * 4);
  int* cursor   = (int*)carve((size_t)N * 4);
  int* deg      = (int*)carve((size_t)N * 4);
  int* bsum     = (int*)carve((size_t)nb * 4);
  int* csr_src  = (int*)carve((size_t)Etot * 4);
  (void)ws_size; (void)n_in; (void)out_size;

  hipMemsetAsync(deg, 0, (size_t)N * 4, stream);
  // prep: W transposes + histogram
  {
    int grid = 128 + 64 + (Etot + 255) / 256;
    prep_kernel<<<grid, 256, 0, stream>>>(W1, W2, ei, Bt1, Bt2, deg, N, E);
  }
  // layer-1 projection (MFMA, in-register fp32->fp16 A) + att coefficients
  {
    dim3 g((N + 127) / 128, 4);
    gemm_mfma_kernel<128, 256, true><<<g, 256, 0, stream>>>(
        x, Bt1, h1h, att_src1, att_dst1, a_src1, a_dst1, N);
  }
  // CSR build
  scan1_kernel<<<nb, 256, 0, stream>>>(deg, bsum, N);
  scan3_kernel<<<nb, 256, 0, stream>>>(deg, bsum, rowptr, cursor, N);
  scatter_kernel<<<(Etot + 255) / 256, 256, 0, stream>>>(ei, E, N, cursor, csr_src);
  // layer-1 aggregation (+bias+ELU, fp16 out)
  agg1_kernel<<<(N + 3) / 4, 256, 0, stream>>>(rowptr, csr_src, a_src1, a_dst1,
                                               (const __half*)h1h, bias1, h_act, N);
  // layer-2 projection (MFMA) + att coefficients
  {
    dim3 g((N + 127) / 128, 1);
    gemm_mfma_kernel<256, 64, false><<<g, 256, 0, stream>>>(
        h_act, Bt2, h2h, att_src2, att_dst2, a_src2, a_dst2, N);
  }
  agg2_kernel<<<(N + 3) / 4, 256, 0, stream>>>(rowptr, csr_src, a_src2, a_dst2,
                                               (const __half*)h2h, bias2, out, N);
}